// Round 1
// baseline (887.686 us; speedup 1.0000x reference)
//
#include <hip/hip_runtime.h>

typedef __bf16 bf16_t;
typedef __bf16 bf16x8 __attribute__((ext_vector_type(8)));
typedef float  f32x4  __attribute__((ext_vector_type(4)));
typedef int    i32x4  __attribute__((ext_vector_type(4)));

#define TT 64
#define PL 136   // padded row stride (elems) for [t][128] bf16 tiles
#define PX 264   // padded row stride (elems) for [t][256] bf16 tiles

__device__ __forceinline__ f32x4 mfma16(bf16x8 a, bf16x8 b, f32x4 c) {
    return __builtin_amdgcn_mfma_f32_16x16x32_bf16(a, b, c, 0, 0, 0);
}

// ---------------- weight conversion to MFMA fragment order ----------------
// frag index: ((mt*KB + kb)*64 + lane)*8 + j  <->  m = mt*16 + (lane&15),
// k = kb*32 + (lane>>4)*8 + j.  src is row-major [M][K].
__global__ void conv_batch(const float* __restrict__ src, bf16_t* __restrict__ dst,
                           int M, int K, int cnt) {
    int idx = blockIdx.x * 256 + threadIdx.x;
    int MK = M * K;
    if (idx >= MK * cnt) return;
    int lay = idx / MK;
    int r = idx - lay * MK;
    int j = r & 7, lane = (r >> 3) & 63, rest = r >> 9;
    int KB = K >> 5;
    int kb = rest % KB, mt = rest / KB;
    int m = mt * 16 + (lane & 15);
    int k = kb * 32 + ((lane >> 4) << 3) + j;
    dst[idx] = (bf16_t)src[(size_t)lay * MK + m * K + k];
}

// dil_w [30][256][128][2] -> per-layer A[256][256]: k<128 tap0(delayed), k>=128 tap1
__global__ void conv_dil(const float* __restrict__ dw, bf16_t* __restrict__ dst) {
    int idx = blockIdx.x * 256 + threadIdx.x;   // 30*65536 total
    int lay = idx >> 16, r = idx & 65535;
    int j = r & 7, lane = (r >> 3) & 63, rest = r >> 9;
    int kb = rest & 7, mt = rest >> 3;
    int m = mt * 16 + (lane & 15);
    int k = kb * 32 + ((lane >> 4) << 3) + j;
    float v = (k < 128) ? dw[(((size_t)lay * 256 + m) * 128 + k) * 2]
                        : dw[(((size_t)lay * 256 + m) * 128 + (k - 128)) * 2 + 1];
    dst[idx] = (bf16_t)v;
}

// ---------------- conditioning precompute ----------------
// block = i*4+n (i==30 -> end2), thread = o. out[(i*4+n)*256+o][16]
__global__ void cond_kernel(const float* __restrict__ cond_w,
                            const float* __restrict__ end2_w,
                            const float* __restrict__ end2_b,
                            const float* __restrict__ en,
                            float* __restrict__ cond_all,
                            float* __restrict__ cond2) {
    __shared__ f32x4 en_s[1024];  // en[n]: [256 c][16 e] as 4 f32x4 per c
    int bi = blockIdx.x;
    int i = bi >> 2, n = bi & 3, o = threadIdx.x;
    const f32x4* ep = (const f32x4*)(en + (size_t)n * 4096);
    for (int idx = threadIdx.x; idx < 1024; idx += 256) en_s[idx] = ep[idx];
    __syncthreads();
    const float* W = (i < 30) ? cond_w + ((size_t)i * 256 + o) * 256
                              : end2_w + (size_t)o * 256;
    f32x4 a0 = {0.f,0.f,0.f,0.f}, a1 = a0, a2 = a0, a3 = a0;
    for (int c = 0; c < 256; c += 4) {
        f32x4 wv = *(const f32x4*)(W + c);
        #pragma unroll
        for (int cc = 0; cc < 4; ++cc) {
            float wf = wv[cc];
            a0 += wf * en_s[(c + cc) * 4 + 0];
            a1 += wf * en_s[(c + cc) * 4 + 1];
            a2 += wf * en_s[(c + cc) * 4 + 2];
            a3 += wf * en_s[(c + cc) * 4 + 3];
        }
    }
    float bias = (i < 30) ? 0.f : end2_b[o];
    float* dst = (i < 30) ? cond_all + (((size_t)i * 4 + n) * 256 + o) * 16
                          : cond2 + ((size_t)n * 256 + o) * 16;
    f32x4* d4 = (f32x4*)dst;
    d4[0] = a0 + bias; d4[1] = a1 + bias; d4[2] = a2 + bias; d4[3] = a3 + bias;
}

// ---------------- start: l0 = start1@x ; s0 = start2@l0 (t>=4096) ----------------
__global__ __launch_bounds__(512) void start_kernel(
    const float* __restrict__ x, bf16_t* __restrict__ l_out,
    float* __restrict__ s, const bf16_t* __restrict__ A1,
    const bf16_t* __restrict__ A2) {
    __shared__ __align__(16) bf16_t xt[TT * PX];
    __shared__ __align__(16) bf16_t l0[TT * PL];
    int tid = threadIdx.x;
    int n = blockIdx.x >> 7, tile = blockIdx.x & 127, t0 = tile * TT;
    int lane = tid & 63, w = tid >> 6, i16 = lane & 15, q = lane >> 4;

    {   // stage x tile transposed -> [t][c] bf16
        int t = tid & 63;
        for (int c = tid >> 6; c < 256; c += 8)
            xt[t * PX + c] = (bf16_t)x[((size_t)n * 256 + c) * 8192 + t0 + t];
    }
    __syncthreads();

    // GEMM l0: M=128 (wave w -> mtile w), K=256
    f32x4 z = {0.f,0.f,0.f,0.f};
    f32x4 acc[4] = {z, z, z, z};
    #pragma unroll
    for (int kb = 0; kb < 8; ++kb) {
        int koff = kb * 32 + q * 8;
        bf16x8 bf[4];
        #pragma unroll
        for (int nt = 0; nt < 4; ++nt)
            bf[nt] = *(const bf16x8*)(xt + (nt * 16 + i16) * PX + koff);
        bf16x8 af = *(const bf16x8*)(A1 + (((size_t)w * 8 + kb) * 64 + lane) * 8);
        #pragma unroll
        for (int nt = 0; nt < 4; ++nt) acc[nt] = mfma16(af, bf[nt], acc[nt]);
    }
    #pragma unroll
    for (int nt = 0; nt < 4; ++nt)
        #pragma unroll
        for (int j = 0; j < 4; ++j)
            l0[(nt * 16 + i16) * PL + w * 16 + q * 4 + j] = (bf16_t)acc[nt][j];
    __syncthreads();

    {   // copy l0 -> global [N][L][128]
        int r = tid >> 4, col = (tid & 15) * 8;
        #pragma unroll
        for (int p = 0; p < 2; ++p) {
            int rr = r + p * 32;
            *(i32x4*)(l_out + ((size_t)n * 8192 + t0 + rr) * 128 + col) =
                *(const i32x4*)(l0 + rr * PL + col);
        }
    }

    if (t0 >= 4096) {  // s0: M=256, K=128
        f32x4 a2[2][4] = {{z,z,z,z},{z,z,z,z}};
        #pragma unroll
        for (int kb = 0; kb < 4; ++kb) {
            int koff = kb * 32 + q * 8;
            bf16x8 bf[4];
            #pragma unroll
            for (int nt = 0; nt < 4; ++nt)
                bf[nt] = *(const bf16x8*)(l0 + (nt * 16 + i16) * PL + koff);
            #pragma unroll
            for (int mt2 = 0; mt2 < 2; ++mt2) {
                bf16x8 af = *(const bf16x8*)(A2 + ((((size_t)2 * w + mt2) * 4 + kb) * 64 + lane) * 8);
                #pragma unroll
                for (int nt = 0; nt < 4; ++nt) a2[mt2][nt] = mfma16(af, bf[nt], a2[mt2][nt]);
            }
        }
        float* sp = s + (size_t)n * 256 * 4096 + (t0 - 4096);
        #pragma unroll
        for (int mt2 = 0; mt2 < 2; ++mt2)
            #pragma unroll
            for (int nt = 0; nt < 4; ++nt)
                #pragma unroll
                for (int j = 0; j < 4; ++j) {
                    int o = (2 * w + mt2) * 16 + q * 4 + j;
                    sp[(size_t)o * 4096 + nt * 16 + i16] = a2[mt2][nt][j];
                }
    }
}

// ---------------- fused WaveNet layer ----------------
__global__ __launch_bounds__(512) void layer_kernel(
    const bf16_t* __restrict__ l_in, bf16_t* __restrict__ l_out,
    float* __restrict__ s,
    const bf16_t* __restrict__ Ad, const bf16_t* __restrict__ Ar,
    const bf16_t* __restrict__ Ak, const float* __restrict__ cond,
    int dil) {
    __shared__ __align__(16) bf16_t l_cur[TT * PL];
    __shared__ __align__(16) bf16_t l_del[TT * PL];
    __shared__ __align__(16) bf16_t g_lds[TT * PL];
    __shared__ __align__(16) float cond_lds[4096];
    __shared__ __align__(16) char u_raw[34304];
    bf16_t* act = (bf16_t*)u_raw;  // [256][66]
    float*  d2  = (float*)u_raw;   // [128][67]

    int tid = threadIdx.x;
    int n = blockIdx.x >> 7, tile = blockIdx.x & 127, t0 = tile * TT;
    int lane = tid & 63, w = tid >> 6, i16 = lane & 15, q = lane >> 4;

    {   // stage l_cur, l_del (delayed by dil, zero-pad), cond
        int r = tid >> 4, col = (tid & 15) * 8;
        size_t base = (size_t)n * 8192;
        #pragma unroll
        for (int p = 0; p < 2; ++p) {
            int rr = r + p * 32;
            *(i32x4*)(l_cur + rr * PL + col) =
                *(const i32x4*)(l_in + (base + t0 + rr) * 128 + col);
            int gp = t0 - dil + rr;
            i32x4 v = {0, 0, 0, 0};
            if (gp >= 0) v = *(const i32x4*)(l_in + (base + gp) * 128 + col);
            *(i32x4*)(l_del + rr * PL + col) = v;
        }
        const f32x4* csrc = (const f32x4*)(cond + (size_t)n * 4096);
        for (int idx = tid; idx < 1024; idx += 512) ((f32x4*)cond_lds)[idx] = csrc[idx];
    }
    __syncthreads();

    // GEMM1: d = [W0 W1] @ [l_del; l_cur]  (M=256, K=256)
    f32x4 z = {0.f,0.f,0.f,0.f};
    f32x4 acc[2][4] = {{z,z,z,z},{z,z,z,z}};
    #pragma unroll
    for (int kb = 0; kb < 8; ++kb) {
        const bf16_t* bsrc = (kb < 4) ? l_del : l_cur;
        int koff = (kb & 3) * 32 + q * 8;
        bf16x8 bf[4];
        #pragma unroll
        for (int nt = 0; nt < 4; ++nt)
            bf[nt] = *(const bf16x8*)(bsrc + (nt * 16 + i16) * PL + koff);
        #pragma unroll
        for (int mt2 = 0; mt2 < 2; ++mt2) {
            bf16x8 af = *(const bf16x8*)(Ad + ((((size_t)2 * w + mt2) * 8 + kb) * 64 + lane) * 8);
            #pragma unroll
            for (int nt = 0; nt < 4; ++nt) acc[mt2][nt] = mfma16(af, bf[nt], acc[mt2][nt]);
        }
    }

    // + cond, activation (waves 0-3: sigmoid(ch 0..127); waves 4-7: tanh(ch 128..255))
    #pragma unroll
    for (int mt2 = 0; mt2 < 2; ++mt2) {
        int o_base = (2 * w + mt2) * 16 + q * 4;
        #pragma unroll
        for (int j = 0; j < 4; ++j) {
            int o = o_base + j;
            float cv = cond_lds[o * 16 + i16];
            #pragma unroll
            for (int nt = 0; nt < 4; ++nt) {
                float v = acc[mt2][nt][j] + cv;
                float a;
                if (w < 4) a = 1.0f / (1.0f + __expf(-v));
                else       a = 1.0f - 2.0f / (1.0f + __expf(2.0f * v));
                act[o * 66 + nt * 16 + i16] = (bf16_t)a;
            }
        }
    }
    __syncthreads();

    {   // gate: g[t][c] = sig[c]*tanh[c+128]
        int c = tid & 127, th = tid >> 7;
        #pragma unroll
        for (int t = th; t < TT; t += 4) {
            float sv = (float)act[c * 66 + t];
            float tv = (float)act[(c + 128) * 66 + t];
            g_lds[t * PL + c] = (bf16_t)(sv * tv);
        }
    }
    __syncthreads();

    // GEMM2 (res, M=128) + GEMM3 (skip, M=256), shared B-fragments, K=128
    f32x4 acc2[4] = {z,z,z,z};
    f32x4 acc3[2][4] = {{z,z,z,z},{z,z,z,z}};
    #pragma unroll
    for (int kb = 0; kb < 4; ++kb) {
        int koff = kb * 32 + q * 8;
        bf16x8 bf[4];
        #pragma unroll
        for (int nt = 0; nt < 4; ++nt)
            bf[nt] = *(const bf16x8*)(g_lds + (nt * 16 + i16) * PL + koff);
        bf16x8 ar = *(const bf16x8*)(Ar + (((size_t)w * 4 + kb) * 64 + lane) * 8);
        #pragma unroll
        for (int nt = 0; nt < 4; ++nt) acc2[nt] = mfma16(ar, bf[nt], acc2[nt]);
        #pragma unroll
        for (int mt2 = 0; mt2 < 2; ++mt2) {
            bf16x8 ak = *(const bf16x8*)(Ak + ((((size_t)2 * w + mt2) * 4 + kb) * 64 + lane) * 8);
            #pragma unroll
            for (int nt = 0; nt < 4; ++nt) acc3[mt2][nt] = mfma16(ak, bf[nt], acc3[mt2][nt]);
        }
    }
    // res matmul result -> d2 (union space; act is dead)
    #pragma unroll
    for (int nt = 0; nt < 4; ++nt)
        #pragma unroll
        for (int j = 0; j < 4; ++j)
            d2[(w * 16 + q * 4 + j) * 67 + nt * 16 + i16] = acc2[nt][j];
    // skip accumulate into s (only t >= 4096 matters for output)
    if (t0 >= 4096) {
        float* sp = s + (size_t)n * 256 * 4096 + (t0 - 4096);
        #pragma unroll
        for (int mt2 = 0; mt2 < 2; ++mt2)
            #pragma unroll
            for (int nt = 0; nt < 4; ++nt)
                #pragma unroll
                for (int j = 0; j < 4; ++j) {
                    int o = (2 * w + mt2) * 16 + q * 4 + j;
                    float* p = sp + (size_t)o * 4096 + nt * 16 + i16;
                    *p += acc3[mt2][nt][j];
                }
    }
    __syncthreads();

    {   // l_out = l_cur + res   (coalesced bf16 store)
        int c = tid & 127, th = tid >> 7;
        #pragma unroll
        for (int t = th; t < TT; t += 4) {
            float lv = (float)l_cur[t * PL + c] + d2[c * 67 + t];
            l_out[((size_t)n * 8192 + t0 + t) * 128 + c] = (bf16_t)lv;
        }
    }
}

// ---------------- end: out = relu(end1@relu(s) + b1 + cond2_tiled) ----------------
__global__ __launch_bounds__(512) void end_kernel(
    const float* __restrict__ s, float* __restrict__ out,
    const bf16_t* __restrict__ Ae, const float* __restrict__ cond2,
    const float* __restrict__ b1) {
    __shared__ __align__(16) bf16_t st[TT * PX];
    __shared__ float c2[4096];
    __shared__ float b1s[256];
    int tid = threadIdx.x;
    int n = blockIdx.x >> 6, tile = blockIdx.x & 63, t0 = tile * TT;
    int lane = tid & 63, w = tid >> 6, i16 = lane & 15, q = lane >> 4;

    {
        int t = tid & 63;
        for (int c = tid >> 6; c < 256; c += 8) {
            float v = s[((size_t)n * 256 + c) * 4096 + t0 + t];
            st[t * PX + c] = (bf16_t)fmaxf(v, 0.f);
        }
        const f32x4* cc = (const f32x4*)(cond2 + (size_t)n * 4096);
        for (int idx = tid; idx < 1024; idx += 512) ((f32x4*)c2)[idx] = cc[idx];
        if (tid < 64) ((f32x4*)b1s)[tid] = ((const f32x4*)b1)[tid];
    }
    __syncthreads();

    f32x4 z = {0.f,0.f,0.f,0.f};
    f32x4 acc[2][4] = {{z,z,z,z},{z,z,z,z}};
    #pragma unroll
    for (int kb = 0; kb < 8; ++kb) {
        int koff = kb * 32 + q * 8;
        bf16x8 bf[4];
        #pragma unroll
        for (int nt = 0; nt < 4; ++nt)
            bf[nt] = *(const bf16x8*)(st + (nt * 16 + i16) * PX + koff);
        #pragma unroll
        for (int mt2 = 0; mt2 < 2; ++mt2) {
            bf16x8 af = *(const bf16x8*)(Ae + ((((size_t)2 * w + mt2) * 8 + kb) * 64 + lane) * 8);
            #pragma unroll
            for (int nt = 0; nt < 4; ++nt) acc[mt2][nt] = mfma16(af, bf[nt], acc[mt2][nt]);
        }
    }
    #pragma unroll
    for (int mt2 = 0; mt2 < 2; ++mt2)
        #pragma unroll
        for (int j = 0; j < 4; ++j) {
            int o = (2 * w + mt2) * 16 + q * 4 + j;
            float bb = b1s[o] + c2[o * 16 + i16];
            #pragma unroll
            for (int nt = 0; nt < 4; ++nt) {
                float v = acc[mt2][nt][j] + bb;
                out[((size_t)n * 256 + o) * 4096 + t0 + nt * 16 + i16] = fmaxf(v, 0.f);
            }
        }
}

extern "C" void kernel_launch(void* const* d_in, const int* in_sizes, int n_in,
                              void* d_out, int out_size, void* d_ws, size_t ws_size,
                              hipStream_t stream) {
    const float* x   = (const float*)d_in[0];
    const float* en  = (const float*)d_in[1];
    const float* s1w = (const float*)d_in[2];
    const float* s2w = (const float*)d_in[3];
    const float* cw  = (const float*)d_in[4];
    const float* dw  = (const float*)d_in[5];
    const float* rw  = (const float*)d_in[6];
    const float* kw  = (const float*)d_in[7];
    const float* e1w = (const float*)d_in[8];
    const float* e1b = (const float*)d_in[9];
    const float* e2w = (const float*)d_in[10];
    const float* e2b = (const float*)d_in[11];
    float* out = (float*)d_out;

    char* p = (char*)d_ws;
    auto take = [&](size_t bytes) {
        char* r = p;
        p += (bytes + 255) & ~(size_t)255;
        return r;
    };
    bf16_t* A1   = (bf16_t*)take((size_t)128 * 256 * 2);
    bf16_t* A2   = (bf16_t*)take((size_t)256 * 128 * 2);
    bf16_t* Ae   = (bf16_t*)take((size_t)256 * 256 * 2);
    bf16_t* Adil = (bf16_t*)take((size_t)30 * 65536 * 2);
    bf16_t* Ares = (bf16_t*)take((size_t)30 * 16384 * 2);
    bf16_t* Askp = (bf16_t*)take((size_t)30 * 32768 * 2);
    float*  condA= (float*)take((size_t)30 * 16384 * 4);
    float*  cond2= (float*)take((size_t)16384 * 4);
    bf16_t* la   = (bf16_t*)take((size_t)4 * 8192 * 128 * 2);
    bf16_t* lb   = (bf16_t*)take((size_t)4 * 8192 * 128 * 2);
    float*  sbuf = (float*)take((size_t)4 * 256 * 4096 * 4);

    conv_batch<<<30 * 16384 / 256, 256, 0, stream>>>(rw, Ares, 128, 128, 30);
    conv_batch<<<30 * 32768 / 256, 256, 0, stream>>>(kw, Askp, 256, 128, 30);
    conv_batch<<<128 * 256 / 256, 256, 0, stream>>>(s1w, A1, 128, 256, 1);
    conv_batch<<<256 * 128 / 256, 256, 0, stream>>>(s2w, A2, 256, 128, 1);
    conv_batch<<<256 * 256 / 256, 256, 0, stream>>>(e1w, Ae, 256, 256, 1);
    conv_dil<<<30 * 65536 / 256, 256, 0, stream>>>(dw, Adil);
    cond_kernel<<<124, 256, 0, stream>>>(cw, e2w, e2b, en, condA, cond2);

    start_kernel<<<512, 512, 0, stream>>>(x, la, sbuf, A1, A2);
    bf16_t* src = la;
    bf16_t* dst = lb;
    for (int i = 0; i < 30; ++i) {
        layer_kernel<<<512, 512, 0, stream>>>(src, dst, sbuf,
            Adil + (size_t)i * 65536, Ares + (size_t)i * 16384,
            Askp + (size_t)i * 32768, condA + (size_t)i * 16384, 1 << (i % 10));
        bf16_t* t = src; src = dst; dst = t;
    }
    end_kernel<<<256, 512, 0, stream>>>(sbuf, out, Ae, cond2, e1b);
}